// Round 9
// baseline (2572.108 us; speedup 1.0000x reference)
//
#include <hip/hip_runtime.h>
#include <math.h>

#define NN 100000
#define EE 1600000
#define F0 166
#define HID 76
#define H3 228
#define CHID 510
#define SLOPE 0.22916666666666666f
#define CAND_MAX 4096
#define NBIN 4096
#define HPAD 20   // h row stride in float4 units (80 floats = 320B = 5 aligned lines)

// bucket-partition CSR build parameters
#define BSH 9
#define BSZ 512                      // nodes per bucket
#define NBKT 196                     // ceil(NN/BSZ); max bucket = 99999>>9 = 195
#define CH 4096                      // edges per partition chunk
#define NCHK 391                     // ceil(EE/CH)
#define NBAND 13                     // src bands of 8192 nodes (2.6MB of h rows ~ L2-sized)
#define AGG_NWG 7422                 // ceil(NN*19/256)

__device__ __forceinline__ unsigned f2key(float f){
    unsigned u = __float_as_uint(f);
    return (u & 0x80000000u) ? ~u : (u | 0x80000000u);
}
__device__ __forceinline__ float key2f(unsigned k){
    unsigned u = (k & 0x80000000u) ? (k & 0x7fffffffu) : ~k;
    return __uint_as_float(u);
}

// ---- scorer norms: invn[i] = 1/||scorer_i|| ----
__global__ void scorer_norms_k(const float* __restrict__ s0, const float* __restrict__ s1,
                               float* __restrict__ outn){
    __shared__ float red[256];
    int tid = threadIdx.x;
    float a = 0.f;
    for (int k = tid; k < F0; k += 256) a += s0[k]*s0[k];
    red[tid] = a; __syncthreads();
    for (int s = 128; s > 0; s >>= 1){ if (tid < s) red[tid] += red[tid+s]; __syncthreads(); }
    if (tid == 0) outn[0] = 1.0f/sqrtf(red[0]);
    __syncthreads();
    float b = 0.f;
    for (int k = tid; k < HID; k += 256) b += s1[k]*s1[k];
    red[tid] = b; __syncthreads();
    for (int s = 128; s > 0; s >>= 1){ if (tid < s) red[tid] += red[tid+s]; __syncthreads(); }
    if (tid == 0) outn[1] = 1.0f/sqrtf(red[0]);
}

// ---- pad/transpose classifier weights: w1t[512][76] (j-major), b1p[512], w2p[1024] ----
__global__ void pad_k(const float* __restrict__ w1, const float* __restrict__ b1,
                      const float* __restrict__ w2, float* __restrict__ w1t,
                      float* __restrict__ b1p, float* __restrict__ w2p){
    int idx = blockIdx.x*256 + threadIdx.x;
    if (idx < 512*HID){
        int j = idx / HID, k = idx - j*HID;
        w1t[idx] = (j < CHID) ? w1[k*CHID + j] : 0.f;
    }
    if (idx < 512)  b1p[idx] = (idx < CHID)   ? b1[idx] : 0.f;
    if (idx < 1024) w2p[idx] = (idx < CHID*2) ? w2[idx] : 0.f;
}

// ================= bucket-partition CSR build (no global atomics) =================

__global__ __launch_bounds__(256) void p1_hist_k(const int* __restrict__ src, const int* __restrict__ dst,
                                                 int* __restrict__ bhS, int* __restrict__ bhD){
    __shared__ int hS[NBKT], hD[NBKT];
    int t = blockIdx.y, blk = blockIdx.x, tid = threadIdx.x;
    for (int i = tid; i < NBKT; i += 256){ hS[i] = 0; hD[i] = 0; }
    __syncthreads();
    size_t ebase = (size_t)t*EE + (size_t)blk*CH;
    int m = EE - blk*CH; if (m > CH) m = CH;
    for (int j = tid; j < m; j += 256){
        atomicAdd(&hS[src[ebase + j] >> BSH], 1);
        atomicAdd(&hD[dst[ebase + j] >> BSH], 1);
    }
    __syncthreads();
    for (int i = tid; i < NBKT; i += 256){
        bhS[((size_t)t*NBKT + i)*NCHK + blk] = hS[i];
        bhD[((size_t)t*NBKT + i)*NCHK + blk] = hD[i];
    }
}

__global__ __launch_bounds__(512) void p2_scan_k(int* __restrict__ bhS, int* __restrict__ bhD,
                                                 int* __restrict__ ctS, int* __restrict__ ctD){
    __shared__ int sd[512];
    int b = blockIdx.x, t = blockIdx.y, tid = threadIdx.x;
    for (int a = 0; a < 2; a++){
        int* bh = a ? bhD : bhS;
        int* ct = a ? ctD : ctS;
        int* row = bh + ((size_t)t*NBKT + b)*NCHK;
        int v = (tid < NCHK) ? row[tid] : 0;
        sd[tid] = v; __syncthreads();
        for (int off = 1; off < 512; off <<= 1){
            int x = (tid >= off) ? sd[tid - off] : 0;
            __syncthreads();
            sd[tid] += x;
            __syncthreads();
        }
        if (tid < NCHK) row[tid] = sd[tid] - v;
        if (tid == 511) ct[t*NBKT + b] = sd[511];
        __syncthreads();
    }
}

__global__ __launch_bounds__(256) void p3_base_k(const int* __restrict__ ctS, const int* __restrict__ ctD,
                                                 int* __restrict__ bbS, int* __restrict__ bbD){
    __shared__ int sd[256];
    int tid = threadIdx.x;
    for (int a = 0; a < 2; a++){
        const int* ct = a ? ctD : ctS;
        int* bb = a ? bbD : bbS;
        for (int t = 0; t < 3; t++){
            int v = (tid < NBKT) ? ct[t*NBKT + tid] : 0;
            sd[tid] = v; __syncthreads();
            for (int off = 1; off < 256; off <<= 1){
                int x = (tid >= off) ? sd[tid - off] : 0;
                __syncthreads();
                sd[tid] += x;
                __syncthreads();
            }
            if (tid < NBKT) bb[t*(NBKT+1) + tid] = sd[tid] - v;
            if (tid == 0)   bb[t*(NBKT+1) + NBKT] = EE;
            __syncthreads();
        }
    }
}

// pass 4: scatter src values (bucketed by src) and PACKED (s<<9 | d&511) pairs
// (bucketed by dst). 17+9=26 bits fits u32 -> halves pairpart traffic vs u64.
__global__ __launch_bounds__(256) void p4_scatter_k(const int* __restrict__ src, const int* __restrict__ dst,
                                                    const int* __restrict__ bhS, const int* __restrict__ bhD,
                                                    const int* __restrict__ bbS, const int* __restrict__ bbD,
                                                    int* __restrict__ srcpart,
                                                    unsigned* __restrict__ pairpart){
    __shared__ int baseS[NBKT], baseD[NBKT], cS[NBKT], cD[NBKT];
    int t = blockIdx.y, blk = blockIdx.x, tid = threadIdx.x;
    for (int i = tid; i < NBKT; i += 256){
        baseS[i] = bbS[t*(NBKT+1) + i] + bhS[((size_t)t*NBKT + i)*NCHK + blk];
        baseD[i] = bbD[t*(NBKT+1) + i] + bhD[((size_t)t*NBKT + i)*NCHK + blk];
        cS[i] = 0; cD[i] = 0;
    }
    __syncthreads();
    size_t ebase = (size_t)t*EE + (size_t)blk*CH;
    int m = EE - blk*CH; if (m > CH) m = CH;
    int* sp = srcpart + (size_t)t*EE;
    unsigned* pp = pairpart + (size_t)t*EE;
    for (int j = tid; j < m; j += 256){
        int s = src[ebase + j], d = dst[ebase + j];
        int bs = s >> BSH, bd = d >> BSH;
        int r0 = atomicAdd(&cS[bs], 1);
        sp[baseS[bs] + r0] = s;
        int r1 = atomicAdd(&cD[bd], 1);
        pp[baseD[bd] + r1] = ((unsigned)s << BSH) | (unsigned)(d & (BSZ-1));
    }
}

__global__ __launch_bounds__(256) void p5_degO_k(const int* __restrict__ srcpart,
                                                 const int* __restrict__ bbS,
                                                 float* __restrict__ nO){
    __shared__ int cnt[BSZ];
    int b = blockIdx.x, t = blockIdx.y, tid = threadIdx.x;
    for (int i = tid; i < BSZ; i += 256) cnt[i] = 0;
    __syncthreads();
    int st = bbS[t*(NBKT+1) + b], en = bbS[t*(NBKT+1) + b + 1];
    const int* sp = srcpart + (size_t)t*EE;
    for (int j = st + tid; j < en; j += 256) atomicAdd(&cnt[sp[j] & (BSZ-1)], 1);
    __syncthreads();
    int nb = b << BSH;
    for (int i = tid; i < BSZ; i += 256){
        int n = nb + i;
        if (n < NN){
            int o = cnt[i]; if (o < 1) o = 1;
            nO[t*NN + n] = 1.0f/sqrtf((float)o);
        }
    }
}

// pass 6: per-bucket deg_in + rs + CSR col fill, SRC-BAND-SORTED within each row.
__global__ __launch_bounds__(512) void p6_csr_k(const unsigned* __restrict__ pairpart,
                                                const int* __restrict__ bbD,
                                                int* __restrict__ degI, int* __restrict__ rs,
                                                float* __restrict__ nI,
                                                int* __restrict__ col){
    __shared__ int cnt2[BSZ*NBAND];
    __shared__ int fc2[BSZ*NBAND];
    __shared__ int sd[BSZ];
    int b = blockIdx.x, t = blockIdx.y, tid = threadIdx.x;
    for (int i = tid; i < BSZ*NBAND; i += 512){ cnt2[i] = 0; fc2[i] = 0; }
    __syncthreads();
    int st = bbD[t*(NBKT+1) + b], en = bbD[t*(NBKT+1) + b + 1];
    const unsigned* pp = pairpart + (size_t)t*EE;
    for (int j = st + tid; j < en; j += 512){
        unsigned p = pp[j];
        int li   = (int)(p & (BSZ-1));
        int band = (int)(p >> (BSH + 13));
        atomicAdd(&cnt2[li*NBAND + band], 1);
    }
    __syncthreads();
    int rowcnt = 0;
    #pragma unroll
    for (int bb = 0; bb < NBAND; bb++) rowcnt += cnt2[tid*NBAND + bb];
    sd[tid] = rowcnt; __syncthreads();
    for (int off = 1; off < 512; off <<= 1){
        int x = (tid >= off) ? sd[tid - off] : 0;
        __syncthreads();
        sd[tid] += x;
        __syncthreads();
    }
    int rowEx = sd[tid] - rowcnt;
    int run = rowEx;
    #pragma unroll
    for (int bb = 0; bb < NBAND; bb++){
        int cvv = cnt2[tid*NBAND + bb];
        cnt2[tid*NBAND + bb] = run;
        run += cvv;
    }
    int nb = b << BSH;
    int n = nb + tid;
    if (n < NN){
        degI[t*NN + n] = rowcnt;
        rs[t*NN + n] = st + rowEx;
        int ii = rowcnt; if (ii < 1) ii = 1;
        nI[t*NN + n] = 1.0f/sqrtf((float)ii);
    }
    __syncthreads();
    int* ct = col + (size_t)t*EE;
    for (int j = st + tid; j < en; j += 512){
        unsigned p = pp[j];
        int s  = (int)(p >> BSH);
        int li = (int)(p & (BSZ-1));
        int band = s >> 13;
        int r = atomicAdd(&fc2[li*NBAND + band], 1);
        ct[st + cnt2[li*NBAND + band] + r] = s;
    }
}

// ==================================================================================

// ---- scores (LDS-staged coalesced) + 12-bit-prefix histogram ----
template<int F, int PAD>
__global__ __launch_bounds__(256) void score_k(const float* __restrict__ x,
                                               const float* __restrict__ scorer,
                                               const float* __restrict__ invn,
                                               float* __restrict__ scores,
                                               unsigned* hist){
    __shared__ float xs[64*PAD];
    __shared__ float part[256];
    int tid = threadIdx.x;
    int n0 = blockIdx.x*64;
    int nodes = NN - n0; if (nodes > 64) nodes = 64;
    for (int idx = tid; idx < nodes*F; idx += 256){
        int n = idx / F, k = idx - n*F;
        xs[n*PAD + k] = x[(size_t)(n0+n)*F + k];
    }
    __syncthreads();
    int w = __builtin_amdgcn_readfirstlane(tid >> 6);
    int lane = tid & 63;
    int k0 = (F*w) >> 2, k1 = (F*(w+1)) >> 2;
    const float* xrow = xs + lane*PAD;
    float s = 0.f;
    for (int k = k0; k < k1; k++) s += xrow[k]*scorer[k];
    part[w*64 + lane] = s;
    __syncthreads();
    if (tid < 64 && n0 + tid < NN){
        float tot = (part[tid] + part[64+tid] + part[128+tid] + part[192+tid]) * invn[0];
        scores[n0 + tid] = tot;
        atomicAdd(&hist[f2key(tot) >> 20], 1u);
    }
}

// ---- compact with fused threshold selection (each block recomputes thr from hist) ----
__global__ __launch_bounds__(256) void compact_k(const float* __restrict__ scores,
                                                 const unsigned* __restrict__ hist,
                                                 float* __restrict__ cv, int* __restrict__ ci, int* cnt){
    __shared__ unsigned cs[256];
    __shared__ int thr_s;
    int tid = threadIdx.x;
    unsigned s = 0;
    int base = NBIN - 1 - tid*16;
    for (int j = 0; j < 16; j++) s += hist[base - j];
    cs[tid] = s; __syncthreads();
    if (tid == 0){
        unsigned acc = 0; int c = 0;
        for (; c < 256; c++){ if (acc + cs[c] >= 76u) break; acc += cs[c]; }
        int b = NBIN - 1 - c*16;
        int sel = 0;
        for (int j = 0; j < 16; j++){
            acc += hist[b - j];
            if (acc >= 76u){ sel = b - j; break; }
        }
        thr_s = sel;
    }
    __syncthreads();
    int thr = thr_s;
    int n = blockIdx.x*256 + tid;
    if (n >= NN) return;
    float sv = scores[n];
    if ((int)(f2key(sv) >> 20) >= thr){
        int p = atomicAdd(cnt, 1);
        if (p < CAND_MAX){ cv[p] = sv; ci[p] = n; }
    }
}

// ---- exact top-76 via O(M^2) rank computation (value desc, index asc) ----
__global__ __launch_bounds__(256) void topk_k(const float* __restrict__ cv,
                                              const int* __restrict__ ci,
                                              const int* __restrict__ cnt,
                                              int* __restrict__ topidx,
                                              float* __restrict__ tanhv){
    __shared__ unsigned long long keys[CAND_MAX];
    int tid = threadIdx.x;
    int M = *cnt; if (M > CAND_MAX) M = CAND_MAX;
    for (int i = tid; i < M; i += 256)
        keys[i] = ((unsigned long long)f2key(cv[i]) << 32) | (unsigned)(~ci[i]);
    __syncthreads();
    for (int i = tid; i < M; i += 256){
        unsigned long long ki = keys[i];
        int r = 0;
        for (int j = 0; j < M; j++) r += (keys[j] > ki) ? 1 : 0;
        if (r < 76){
            topidx[r] = (int)(~(unsigned)(ki & 0xffffffffu));
            tanhv[r]  = tanhf(key2f((unsigned)(ki >> 32)));
        }
    }
}

// ---- GRU weight evolution, one block per matrix row, in-place; also emits Wt ----
template<int F>
__global__ void gru_k(const float* __restrict__ cur, const int* __restrict__ topidx,
                      const float* __restrict__ tanhv, float* __restrict__ W,
                      float* __restrict__ Wt,
                      const float* __restrict__ wih, const float* __restrict__ whh,
                      const float* __restrict__ bih, const float* __restrict__ bhh){
    __shared__ float xr[HID], hr[HID], gx[H3], gh[H3];
    int r = blockIdx.x, tid = threadIdx.x;
    if (tid < HID){
        xr[tid] = cur[(size_t)topidx[tid]*F + r] * tanhv[tid];
        hr[tid] = W[r*HID + tid];
    }
    __syncthreads();
    if (tid < H3){
        const float* wi = wih + tid*HID;
        const float* wh = whh + tid*HID;
        float sa = 0.f, sb = 0.f;
        for (int k = 0; k < HID; k++){ sa += xr[k]*wi[k]; sb += hr[k]*wh[k]; }
        gx[tid] = bih[tid] + sa;
        gh[tid] = bhh[tid] + sb;
    }
    __syncthreads();
    if (tid < HID){
        float rr = 1.f/(1.f + expf(-(gx[tid] + gh[tid])));
        float zz = 1.f/(1.f + expf(-(gx[HID+tid] + gh[HID+tid])));
        float nn = tanhf(gx[2*HID+tid] + rr*gh[2*HID+tid]);
        float nv = (1.f - zz)*nn + zz*hr[tid];
        W[r*HID + tid] = nv;
        int c = tid >> 2, i = tid & 3;
        Wt[(c*F + r)*4 + i] = nv;    // chunk layout for gemm_k
    }
}

// ---- h = (x @ W) * norm_out ----
template<int F, int PAD, int NB>
__global__ __launch_bounds__(256) void gemm_k(const float* __restrict__ x,
                                              const float* __restrict__ Wt,
                                              const float* __restrict__ nO,
                                              float* __restrict__ h){
    __shared__ __align__(16) float xs[NB*PAD];
    int tid = threadIdx.x;
    int n0 = blockIdx.x*NB;
    int nodes = NN - n0; if (nodes > NB) nodes = NB;
    for (int idx = tid; idx < nodes*F; idx += 256){
        int n = idx / F, k = idx - n*F;
        xs[n*PAD + k] = x[(size_t)(n0+n)*F + k];
    }
    __syncthreads();
    int w = __builtin_amdgcn_readfirstlane(tid >> 6);
    int lane = tid & 63;
    int c0 = w*5;
    const float4* Wt4 = (const float4*)Wt;
    float4 accA[5], accB[5];
    #pragma unroll
    for (int c = 0; c < 5; c++){
        accA[c] = make_float4(0.f,0.f,0.f,0.f);
        accB[c] = make_float4(0.f,0.f,0.f,0.f);
    }
    const float* xA = xs + lane*PAD;
    const float* xB = xs + ((NB==128) ? (lane+64)*PAD : lane*PAD);
    for (int k = 0; k < F; k++){
        float xa = xA[k];
        float xb = 0.f;
        if constexpr (NB == 128) xb = xB[k];
        #pragma unroll
        for (int c = 0; c < 5; c++){
            float4 wv = Wt4[(c0 + c)*F + k];
            accA[c].x += xa*wv.x; accA[c].y += xa*wv.y;
            accA[c].z += xa*wv.z; accA[c].w += xa*wv.w;
            if constexpr (NB == 128){
                accB[c].x += xb*wv.x; accB[c].y += xb*wv.y;
                accB[c].z += xb*wv.z; accB[c].w += xb*wv.w;
            }
        }
    }
    int nc = (w == 3) ? 4 : 5;
    int nA = n0 + lane;
    if (nA < NN){
        float nm = nO[nA];
        float4* h4 = (float4*)h + (size_t)nA*HPAD + c0;
        for (int c = 0; c < nc; c++){
            float4 a = accA[c];
            h4[c] = make_float4(a.x*nm, a.y*nm, a.z*nm, a.w*nm);
        }
    }
    if constexpr (NB == 128){
        int nB = n0 + 64 + lane;
        if (nB < NN){
            float nm = nO[nB];
            float4* h4 = (float4*)h + (size_t)nB*HPAD + c0;
            for (int c = 0; c < nc; c++){
                float4 a = accB[c];
                h4[c] = make_float4(a.x*nm, a.y*nm, a.z*nm, a.w*nm);
            }
        }
    }
}

// ---- CSR aggregation + dst-norm + leaky, thread per (node, float4 chunk) ----
// col band-sorted (p6) + bijective XCD swizzle + 8-deep gather unroll.
__global__ __launch_bounds__(256) void agg_k(const int* __restrict__ rs, const int* __restrict__ degI,
                      const int* __restrict__ col, const float* __restrict__ h,
                      const float* __restrict__ nI, float* __restrict__ ft){
    int b0 = blockIdx.x;
    int xcd = b0 & 7, i0 = b0 >> 3;
    const int q = AGG_NWG >> 3;          // 927
    const int r8 = AGG_NWG & 7;          // 6
    int bs = (xcd < r8) ? (xcd*(q+1) + i0) : (r8*(q+1) + (xcd - r8)*q + i0);
    int idx = bs*256 + threadIdx.x;
    if (idx >= NN*19) return;
    int n = idx/19, c = idx - n*19;
    int st = rs[n], cnt = degI[n];
    const float4* h4 = (const float4*)h;
    float ax=0.f, ay=0.f, az=0.f, aw=0.f;
    int e = 0;
    for (; e + 8 <= cnt; e += 8){
        int s0 = col[st + e];
        int s1 = col[st + e + 1];
        int s2 = col[st + e + 2];
        int s3 = col[st + e + 3];
        int s4 = col[st + e + 4];
        int s5 = col[st + e + 5];
        int s6 = col[st + e + 6];
        int s7 = col[st + e + 7];
        float4 v0 = h4[(size_t)s0*HPAD + c];
        float4 v1 = h4[(size_t)s1*HPAD + c];
        float4 v2 = h4[(size_t)s2*HPAD + c];
        float4 v3 = h4[(size_t)s3*HPAD + c];
        float4 v4 = h4[(size_t)s4*HPAD + c];
        float4 v5 = h4[(size_t)s5*HPAD + c];
        float4 v6 = h4[(size_t)s6*HPAD + c];
        float4 v7 = h4[(size_t)s7*HPAD + c];
        ax += ((v0.x + v1.x) + (v2.x + v3.x)) + ((v4.x + v5.x) + (v6.x + v7.x));
        ay += ((v0.y + v1.y) + (v2.y + v3.y)) + ((v4.y + v5.y) + (v6.y + v7.y));
        az += ((v0.z + v1.z) + (v2.z + v3.z)) + ((v4.z + v5.z) + (v6.z + v7.z));
        aw += ((v0.w + v1.w) + (v2.w + v3.w)) + ((v4.w + v5.w) + (v6.w + v7.w));
    }
    for (; e + 2 <= cnt; e += 2){
        int s0 = col[st + e];
        int s1 = col[st + e + 1];
        float4 v0 = h4[(size_t)s0*HPAD + c];
        float4 v1 = h4[(size_t)s1*HPAD + c];
        ax += v0.x + v1.x; ay += v0.y + v1.y;
        az += v0.z + v1.z; aw += v0.w + v1.w;
    }
    if (e < cnt){
        int s = col[st + e];
        float4 v = h4[(size_t)s*HPAD + c];
        ax += v.x; ay += v.y; az += v.z; aw += v.w;
    }
    float nm = nI[n];
    ax*=nm; ay*=nm; az*=nm; aw*=nm;
    ax = ax >= 0.f ? ax : ax*SLOPE;
    ay = ay >= 0.f ? ay : ay*SLOPE;
    az = az >= 0.f ? az : az*SLOPE;
    aw = aw >= 0.f ? aw : aw*SLOPE;
    ((float4*)ft)[(size_t)n*19 + c] = make_float4(ax,ay,az,aw);
}

// ---- classifier MLP v5: SCALAR-PATH WEIGHTS.
// Wave wc owns j in [wc*128, wc*128+128); j-loop address is wave-uniform ->
// compiler emits s_load (SGPR weights), v_fma consumes the SGPR operand
// directly. Each lane holds its node's x-row in 19 float4 VGPRs; zero
// per-lane weight loads in the inner loop. Waves own disjoint j -> no shfl
// reduce, just a 4-way LDS combine. Dot uses 4 independent component chains.
__global__ __launch_bounds__(256) void mlp5_k(const float* __restrict__ ft,
                                              const float* __restrict__ w1t,
                                              const float* __restrict__ b1p,
                                              const float* __restrict__ w2p,
                                              const float* __restrict__ b2,
                                              float* __restrict__ out){
    __shared__ __align__(16) float xs[64*HID];   // 19456 B
    __shared__ float red[4*64*2];                // 2048 B
    int tid = threadIdx.x;
    int n0 = blockIdx.x*64;
    {
        int rem = NN - n0; if (rem > 64) rem = 64;
        int lim = rem*19;
        const float4* g4 = (const float4*)(ft + (size_t)n0*HID);
        float4* s4 = (float4*)xs;
        for (int i = tid; i < 64*19; i += 256)
            s4[i] = (i < lim) ? g4[i] : make_float4(0.f,0.f,0.f,0.f);
    }
    __syncthreads();
    int wc = __builtin_amdgcn_readfirstlane(tid >> 6);
    int lane = tid & 63;
    // lane-private x row in VGPRs
    float4 xr[19];
    {
        const float4* xrow = (const float4*)(xs + lane*HID);
        #pragma unroll
        for (int k = 0; k < 19; k++) xr[k] = xrow[k];
    }
    float p0 = 0.f, p1 = 0.f;
    const int jb = wc*128;
    const float4* wbase = (const float4*)(w1t) + (size_t)jb*19;
    #pragma unroll 2
    for (int jj = 0; jj < 128; jj++){
        const float4* wr = wbase + jj*19;       // wave-uniform address
        float sx = 0.f, sy = 0.f, sz = 0.f, sw = 0.f;
        #pragma unroll
        for (int k = 0; k < 19; k++){
            float4 w = wr[k];
            sx += xr[k].x*w.x;
            sy += xr[k].y*w.y;
            sz += xr[k].z*w.z;
            sw += xr[k].w*w.w;
        }
        int j = jb + jj;
        float s = (sx + sy) + (sz + sw) + b1p[j];
        s = fmaxf(s, 0.f);
        p0 += s*w2p[2*j];
        p1 += s*w2p[2*j+1];
    }
    red[(wc*64 + lane)*2 + 0] = p0;
    red[(wc*64 + lane)*2 + 1] = p1;
    __syncthreads();
    if (tid < 128){
        int nl = tid >> 1, comp = tid & 1;
        float v = red[(0*64 + nl)*2 + comp] + red[(1*64 + nl)*2 + comp]
                + red[(2*64 + nl)*2 + comp] + red[(3*64 + nl)*2 + comp] + b2[comp];
        int n = n0 + nl;
        if (n < NN) out[(size_t)n*2 + comp] = v;
    }
}

extern "C" void kernel_launch(void* const* d_in, const int* in_sizes, int n_in,
                              void* d_out, int out_size, void* d_ws, size_t ws_size,
                              hipStream_t stream)
{
    (void)in_sizes; (void)n_in; (void)out_size; (void)ws_size;
    const float* feats   = (const float*)d_in[0];
    const int*   src     = (const int*)d_in[1];
    const int*   dst     = (const int*)d_in[2];
    const float* scorer0 = (const float*)d_in[3];
    const float* scorer1 = (const float*)d_in[4];
    const float* gcnw[2] = {(const float*)d_in[5],  (const float*)d_in[6]};
    const float* wih[2]  = {(const float*)d_in[7],  (const float*)d_in[11]};
    const float* whh[2]  = {(const float*)d_in[8],  (const float*)d_in[12]};
    const float* bih[2]  = {(const float*)d_in[9],  (const float*)d_in[13]};
    const float* bhh[2]  = {(const float*)d_in[10], (const float*)d_in[14]};
    const float* w1 = (const float*)d_in[15];
    const float* b1 = (const float*)d_in[16];
    const float* w2 = (const float*)d_in[17];
    const float* b2 = (const float*)d_in[18];
    float* out = (float*)d_out;

    char* p = (char*)d_ws;
    auto alloc = [&](size_t bytes) -> void* {
        void* r = (void*)p;
        p += (bytes + 255) & ~(size_t)255;
        return r;
    };
    float* ft[3];
    for (int t = 0; t < 3; t++) ft[t] = (float*)alloc((size_t)NN*HID*4);
    float* hbuf    = (float*)alloc((size_t)NN*HPAD*16);
    int*   col_all = (int*)alloc((size_t)3*EE*4);
    float* nO_all  = (float*)alloc((size_t)3*NN*4);
    float* nI_all  = (float*)alloc((size_t)3*NN*4);
    int*   rs_all  = (int*)alloc((size_t)3*NN*4);
    int*   dI_all  = (int*)alloc((size_t)3*NN*4);
    // partition workspace
    int* srcpart = (int*)alloc((size_t)3*EE*4);
    unsigned* pairpart = (unsigned*)alloc((size_t)3*EE*4);
    int* bhS = (int*)alloc((size_t)3*NBKT*NCHK*4);
    int* bhD = (int*)alloc((size_t)3*NBKT*NCHK*4);
    int* ctS = (int*)alloc((size_t)3*NBKT*4);
    int* ctD = (int*)alloc((size_t)3*NBKT*4);
    int* bbS = (int*)alloc((size_t)3*(NBKT+1)*4);
    int* bbD = (int*)alloc((size_t)3*(NBKT+1)*4);

    float*    scores = (float*)alloc((size_t)NN*4);
    float*    cv     = (float*)alloc(CAND_MAX*4);
    int*      ci     = (int*)alloc(CAND_MAX*4);
    int*      topidx = (int*)alloc(128*4);
    float*    tanhv  = (float*)alloc(128*4);
    float*    Wbuf   = (float*)alloc((size_t)F0*HID*4 + 256);
    float*    Wt     = (float*)alloc((size_t)19*F0*16 + 4096);
    float*    invn   = (float*)alloc(256);
    float*    w1t    = (float*)alloc((size_t)512*HID*4);
    float*    b1p    = (float*)alloc(512*4);
    float*    w2p    = (float*)alloc(1024*4);

    // ---- contiguous zero arena (one memset) ----
    char* zbase = p;
    unsigned* hist6 = (unsigned*)alloc((size_t)6*NBIN*4);
    int*      ccnt6 = (int*)alloc(6*256);
    size_t zsize = (size_t)(p - zbase);

    const int gN  = (NN + 255)/256;
    const int gB  = (NN + 63)/64;
    const int gB2 = (NN + 127)/128;
    const int gP  = (512*HID + 255)/256;

    hipMemsetAsync(zbase, 0, zsize, stream);
    scorer_norms_k<<<1,256,0,stream>>>(scorer0, scorer1, invn);
    pad_k<<<gP,256,0,stream>>>(w1, b1, w2, w1t, b1p, w2p);

    // ---- bucket-partition CSR build (no global atomics) ----
    p1_hist_k<<<dim3(NCHK,3),256,0,stream>>>(src, dst, bhS, bhD);
    p2_scan_k<<<dim3(NBKT,3),512,0,stream>>>(bhS, bhD, ctS, ctD);
    p3_base_k<<<1,256,0,stream>>>(ctS, ctD, bbS, bbD);
    p4_scatter_k<<<dim3(NCHK,3),256,0,stream>>>(src, dst, bhS, bhD, bbS, bbD, srcpart, pairpart);
    p5_degO_k<<<dim3(NBKT,3),256,0,stream>>>(srcpart, bbS, nO_all);
    p6_csr_k<<<dim3(NBKT,3),512,0,stream>>>(pairpart, bbD, dI_all, rs_all, nI_all, col_all);

    for (int i = 0; i < 2; i++){
        hipMemcpyAsync(Wbuf, gcnw[i], (size_t)((i==0)?F0:HID)*HID*4, hipMemcpyDeviceToDevice, stream);
        for (int t = 0; t < 3; t++){
            int q = i*3 + t;
            unsigned* hist = hist6 + (size_t)q*NBIN;
            int* ccnt = ccnt6 + q*64;
            const float* cur = (i == 0) ? (feats + (size_t)t*NN*F0) : ft[t];
            if (i == 0) score_k<F0,167><<<gB,256,0,stream>>>(cur, scorer0, invn+0, scores, hist);
            else        score_k<HID,77><<<gB,256,0,stream>>>(cur, scorer1, invn+1, scores, hist);
            compact_k<<<gN,256,0,stream>>>(scores, hist, cv, ci, ccnt);
            topk_k<<<1,256,0,stream>>>(cv, ci, ccnt, topidx, tanhv);
            if (i == 0){
                gru_k<F0><<<F0,256,0,stream>>>(cur, topidx, tanhv, Wbuf, Wt, wih[i], whh[i], bih[i], bhh[i]);
                gemm_k<F0,167,64><<<gB,256,0,stream>>>(cur, Wt, nO_all + (size_t)t*NN, hbuf);
            } else {
                gru_k<HID><<<HID,256,0,stream>>>(cur, topidx, tanhv, Wbuf, Wt, wih[i], whh[i], bih[i], bhh[i]);
                gemm_k<HID,77,128><<<gB2,256,0,stream>>>(cur, Wt, nO_all + (size_t)t*NN, hbuf);
            }
            agg_k<<<AGG_NWG,256,0,stream>>>(rs_all + (size_t)t*NN, dI_all + (size_t)t*NN,
                                            col_all + (size_t)t*EE, hbuf, nI_all + (size_t)t*NN, ft[t]);
        }
    }

    mlp5_k<<<gB,256,0,stream>>>(ft[2], w1t, b1p, w2p, b2, out);
}

// Round 11
// 2241.915 us; speedup vs baseline: 1.1473x; 1.1473x over previous
//
#include <hip/hip_runtime.h>
#include <math.h>

#define NN 100000
#define EE 1600000
#define F0 166
#define HID 76
#define H3 228
#define CHID 510
#define SLOPE 0.22916666666666666f
#define CAND_MAX 4096
#define NBIN 4096
#define HPAD 20   // h row stride in float4 units (80 floats = 320B = 5 aligned lines)

// bucket-partition CSR build parameters
#define BSH 9
#define BSZ 512                      // nodes per bucket
#define NBKT 196                     // ceil(NN/BSZ); max bucket = 99999>>9 = 195
#define CH 4096                      // edges per partition chunk
#define NCHK 391                     // ceil(EE/CH)
#define NBAND 13                     // src bands of 8192 nodes (2.6MB of h rows ~ L2-sized)
#define AGG_NWG 7422                 // ceil(NN*19/256)

__device__ __forceinline__ unsigned f2key(float f){
    unsigned u = __float_as_uint(f);
    return (u & 0x80000000u) ? ~u : (u | 0x80000000u);
}
__device__ __forceinline__ float key2f(unsigned k){
    unsigned u = (k & 0x80000000u) ? (k & 0x7fffffffu) : ~k;
    return __uint_as_float(u);
}

// ---- scorer norms: invn[i] = 1/||scorer_i|| ----
__global__ void scorer_norms_k(const float* __restrict__ s0, const float* __restrict__ s1,
                               float* __restrict__ outn){
    __shared__ float red[256];
    int tid = threadIdx.x;
    float a = 0.f;
    for (int k = tid; k < F0; k += 256) a += s0[k]*s0[k];
    red[tid] = a; __syncthreads();
    for (int s = 128; s > 0; s >>= 1){ if (tid < s) red[tid] += red[tid+s]; __syncthreads(); }
    if (tid == 0) outn[0] = 1.0f/sqrtf(red[0]);
    __syncthreads();
    float b = 0.f;
    for (int k = tid; k < HID; k += 256) b += s1[k]*s1[k];
    red[tid] = b; __syncthreads();
    for (int s = 128; s > 0; s >>= 1){ if (tid < s) red[tid] += red[tid+s]; __syncthreads(); }
    if (tid == 0) outn[1] = 1.0f/sqrtf(red[0]);
}

// ---- pad/transpose classifier weights: w1t[512][76] (j-major), b1p[512], w2p[1024] ----
__global__ void pad_k(const float* __restrict__ w1, const float* __restrict__ b1,
                      const float* __restrict__ w2, float* __restrict__ w1t,
                      float* __restrict__ b1p, float* __restrict__ w2p){
    int idx = blockIdx.x*256 + threadIdx.x;
    if (idx < 512*HID){
        int j = idx / HID, k = idx - j*HID;
        w1t[idx] = (j < CHID) ? w1[k*CHID + j] : 0.f;
    }
    if (idx < 512)  b1p[idx] = (idx < CHID)   ? b1[idx] : 0.f;
    if (idx < 1024) w2p[idx] = (idx < CHID*2) ? w2[idx] : 0.f;
}

// ================= bucket-partition CSR build (no global atomics) =================

__global__ __launch_bounds__(256) void p1_hist_k(const int* __restrict__ src, const int* __restrict__ dst,
                                                 int* __restrict__ bhS, int* __restrict__ bhD){
    __shared__ int hS[NBKT], hD[NBKT];
    int t = blockIdx.y, blk = blockIdx.x, tid = threadIdx.x;
    for (int i = tid; i < NBKT; i += 256){ hS[i] = 0; hD[i] = 0; }
    __syncthreads();
    size_t ebase = (size_t)t*EE + (size_t)blk*CH;
    int m = EE - blk*CH; if (m > CH) m = CH;
    for (int j = tid; j < m; j += 256){
        atomicAdd(&hS[src[ebase + j] >> BSH], 1);
        atomicAdd(&hD[dst[ebase + j] >> BSH], 1);
    }
    __syncthreads();
    for (int i = tid; i < NBKT; i += 256){
        bhS[((size_t)t*NBKT + i)*NCHK + blk] = hS[i];
        bhD[((size_t)t*NBKT + i)*NCHK + blk] = hD[i];
    }
}

__global__ __launch_bounds__(512) void p2_scan_k(int* __restrict__ bhS, int* __restrict__ bhD,
                                                 int* __restrict__ ctS, int* __restrict__ ctD){
    __shared__ int sd[512];
    int b = blockIdx.x, t = blockIdx.y, tid = threadIdx.x;
    for (int a = 0; a < 2; a++){
        int* bh = a ? bhD : bhS;
        int* ct = a ? ctD : ctS;
        int* row = bh + ((size_t)t*NBKT + b)*NCHK;
        int v = (tid < NCHK) ? row[tid] : 0;
        sd[tid] = v; __syncthreads();
        for (int off = 1; off < 512; off <<= 1){
            int x = (tid >= off) ? sd[tid - off] : 0;
            __syncthreads();
            sd[tid] += x;
            __syncthreads();
        }
        if (tid < NCHK) row[tid] = sd[tid] - v;
        if (tid == 511) ct[t*NBKT + b] = sd[511];
        __syncthreads();
    }
}

__global__ __launch_bounds__(256) void p3_base_k(const int* __restrict__ ctS, const int* __restrict__ ctD,
                                                 int* __restrict__ bbS, int* __restrict__ bbD){
    __shared__ int sd[256];
    int tid = threadIdx.x;
    for (int a = 0; a < 2; a++){
        const int* ct = a ? ctD : ctS;
        int* bb = a ? bbD : bbS;
        for (int t = 0; t < 3; t++){
            int v = (tid < NBKT) ? ct[t*NBKT + tid] : 0;
            sd[tid] = v; __syncthreads();
            for (int off = 1; off < 256; off <<= 1){
                int x = (tid >= off) ? sd[tid - off] : 0;
                __syncthreads();
                sd[tid] += x;
                __syncthreads();
            }
            if (tid < NBKT) bb[t*(NBKT+1) + tid] = sd[tid] - v;
            if (tid == 0)   bb[t*(NBKT+1) + NBKT] = EE;
            __syncthreads();
        }
    }
}

// pass 4: scatter src values (bucketed by src) and PACKED (s<<9 | d&511) pairs
__global__ __launch_bounds__(256) void p4_scatter_k(const int* __restrict__ src, const int* __restrict__ dst,
                                                    const int* __restrict__ bhS, const int* __restrict__ bhD,
                                                    const int* __restrict__ bbS, const int* __restrict__ bbD,
                                                    int* __restrict__ srcpart,
                                                    unsigned* __restrict__ pairpart){
    __shared__ int baseS[NBKT], baseD[NBKT], cS[NBKT], cD[NBKT];
    int t = blockIdx.y, blk = blockIdx.x, tid = threadIdx.x;
    for (int i = tid; i < NBKT; i += 256){
        baseS[i] = bbS[t*(NBKT+1) + i] + bhS[((size_t)t*NBKT + i)*NCHK + blk];
        baseD[i] = bbD[t*(NBKT+1) + i] + bhD[((size_t)t*NBKT + i)*NCHK + blk];
        cS[i] = 0; cD[i] = 0;
    }
    __syncthreads();
    size_t ebase = (size_t)t*EE + (size_t)blk*CH;
    int m = EE - blk*CH; if (m > CH) m = CH;
    int* sp = srcpart + (size_t)t*EE;
    unsigned* pp = pairpart + (size_t)t*EE;
    for (int j = tid; j < m; j += 256){
        int s = src[ebase + j], d = dst[ebase + j];
        int bs = s >> BSH, bd = d >> BSH;
        int r0 = atomicAdd(&cS[bs], 1);
        sp[baseS[bs] + r0] = s;
        int r1 = atomicAdd(&cD[bd], 1);
        pp[baseD[bd] + r1] = ((unsigned)s << BSH) | (unsigned)(d & (BSZ-1));
    }
}

__global__ __launch_bounds__(256) void p5_degO_k(const int* __restrict__ srcpart,
                                                 const int* __restrict__ bbS,
                                                 float* __restrict__ nO){
    __shared__ int cnt[BSZ];
    int b = blockIdx.x, t = blockIdx.y, tid = threadIdx.x;
    for (int i = tid; i < BSZ; i += 256) cnt[i] = 0;
    __syncthreads();
    int st = bbS[t*(NBKT+1) + b], en = bbS[t*(NBKT+1) + b + 1];
    const int* sp = srcpart + (size_t)t*EE;
    for (int j = st + tid; j < en; j += 256) atomicAdd(&cnt[sp[j] & (BSZ-1)], 1);
    __syncthreads();
    int nb = b << BSH;
    for (int i = tid; i < BSZ; i += 256){
        int n = nb + i;
        if (n < NN){
            int o = cnt[i]; if (o < 1) o = 1;
            nO[t*NN + n] = 1.0f/sqrtf((float)o);
        }
    }
}

// pass 6: per-bucket deg_in + rs + CSR col fill, SRC-BAND-SORTED within each row.
__global__ __launch_bounds__(512) void p6_csr_k(const unsigned* __restrict__ pairpart,
                                                const int* __restrict__ bbD,
                                                int* __restrict__ degI, int* __restrict__ rs,
                                                float* __restrict__ nI,
                                                int* __restrict__ col){
    __shared__ int cnt2[BSZ*NBAND];
    __shared__ int fc2[BSZ*NBAND];
    __shared__ int sd[BSZ];
    int b = blockIdx.x, t = blockIdx.y, tid = threadIdx.x;
    for (int i = tid; i < BSZ*NBAND; i += 512){ cnt2[i] = 0; fc2[i] = 0; }
    __syncthreads();
    int st = bbD[t*(NBKT+1) + b], en = bbD[t*(NBKT+1) + b + 1];
    const unsigned* pp = pairpart + (size_t)t*EE;
    for (int j = st + tid; j < en; j += 512){
        unsigned p = pp[j];
        int li   = (int)(p & (BSZ-1));
        int band = (int)(p >> (BSH + 13));
        atomicAdd(&cnt2[li*NBAND + band], 1);
    }
    __syncthreads();
    int rowcnt = 0;
    #pragma unroll
    for (int bb = 0; bb < NBAND; bb++) rowcnt += cnt2[tid*NBAND + bb];
    sd[tid] = rowcnt; __syncthreads();
    for (int off = 1; off < 512; off <<= 1){
        int x = (tid >= off) ? sd[tid - off] : 0;
        __syncthreads();
        sd[tid] += x;
        __syncthreads();
    }
    int rowEx = sd[tid] - rowcnt;
    int run = rowEx;
    #pragma unroll
    for (int bb = 0; bb < NBAND; bb++){
        int cvv = cnt2[tid*NBAND + bb];
        cnt2[tid*NBAND + bb] = run;
        run += cvv;
    }
    int nb = b << BSH;
    int n = nb + tid;
    if (n < NN){
        degI[t*NN + n] = rowcnt;
        rs[t*NN + n] = st + rowEx;
        int ii = rowcnt; if (ii < 1) ii = 1;
        nI[t*NN + n] = 1.0f/sqrtf((float)ii);
    }
    __syncthreads();
    int* ct = col + (size_t)t*EE;
    for (int j = st + tid; j < en; j += 512){
        unsigned p = pp[j];
        int s  = (int)(p >> BSH);
        int li = (int)(p & (BSZ-1));
        int band = s >> 13;
        int r = atomicAdd(&fc2[li*NBAND + band], 1);
        ct[st + cnt2[li*NBAND + band] + r] = s;
    }
}

// ==================================================================================

// ---- scores + histogram, BATCHED over t via blockIdx.y ----
template<int F, int PAD>
__global__ __launch_bounds__(256) void score_k(const float* __restrict__ xbase,
                                               const float* __restrict__ scorer,
                                               const float* __restrict__ invn,
                                               float* __restrict__ scores_all,
                                               unsigned* __restrict__ hist_all){
    __shared__ float xs[64*PAD];
    __shared__ float part[256];
    int t = blockIdx.y;
    const float* x = xbase + (size_t)t*NN*F;
    float* scores = scores_all + (size_t)t*NN;
    unsigned* hist = hist_all + (size_t)t*NBIN;
    int tid = threadIdx.x;
    int n0 = blockIdx.x*64;
    int nodes = NN - n0; if (nodes > 64) nodes = 64;
    for (int idx = tid; idx < nodes*F; idx += 256){
        int n = idx / F, k = idx - n*F;
        xs[n*PAD + k] = x[(size_t)(n0+n)*F + k];
    }
    __syncthreads();
    int w = __builtin_amdgcn_readfirstlane(tid >> 6);
    int lane = tid & 63;
    int k0 = (F*w) >> 2, k1 = (F*(w+1)) >> 2;
    const float* xrow = xs + lane*PAD;
    float s = 0.f;
    for (int k = k0; k < k1; k++) s += xrow[k]*scorer[k];
    part[w*64 + lane] = s;
    __syncthreads();
    if (tid < 64 && n0 + tid < NN){
        float tot = (part[tid] + part[64+tid] + part[128+tid] + part[192+tid]) * invn[0];
        scores[n0 + tid] = tot;
        atomicAdd(&hist[f2key(tot) >> 20], 1u);
    }
}

// ---- compact (fused threshold recompute), BATCHED over t via blockIdx.y ----
__global__ __launch_bounds__(256) void compact_k(const float* __restrict__ scores_all,
                                                 const unsigned* __restrict__ hist_all,
                                                 float* __restrict__ cv_all, int* __restrict__ ci_all,
                                                 int* __restrict__ cnt_all){
    __shared__ unsigned cs[256];
    __shared__ int thr_s;
    int t = blockIdx.y;
    const float* scores = scores_all + (size_t)t*NN;
    const unsigned* hist = hist_all + (size_t)t*NBIN;
    float* cv = cv_all + (size_t)t*CAND_MAX;
    int*   ci = ci_all + (size_t)t*CAND_MAX;
    int*   cnt = cnt_all + t*64;
    int tid = threadIdx.x;
    unsigned s = 0;
    int base = NBIN - 1 - tid*16;
    for (int j = 0; j < 16; j++) s += hist[base - j];
    cs[tid] = s; __syncthreads();
    if (tid == 0){
        unsigned acc = 0; int c = 0;
        for (; c < 256; c++){ if (acc + cs[c] >= 76u) break; acc += cs[c]; }
        int b = NBIN - 1 - c*16;
        int sel = 0;
        for (int j = 0; j < 16; j++){
            acc += hist[b - j];
            if (acc >= 76u){ sel = b - j; break; }
        }
        thr_s = sel;
    }
    __syncthreads();
    int thr = thr_s;
    int n = blockIdx.x*256 + tid;
    if (n >= NN) return;
    float sv = scores[n];
    if ((int)(f2key(sv) >> 20) >= thr){
        int p = atomicAdd(cnt, 1);
        if (p < CAND_MAX){ cv[p] = sv; ci[p] = n; }
    }
}

// ---- exact top-76, BATCHED: blockIdx.x = t (3 concurrent 1-block selections) ----
__global__ __launch_bounds__(256) void topk_k(const float* __restrict__ cv_all,
                                              const int* __restrict__ ci_all,
                                              const int* __restrict__ cnt_all,
                                              int* __restrict__ topidx_all,
                                              float* __restrict__ tanhv_all){
    __shared__ unsigned long long keys[CAND_MAX];
    int t = blockIdx.x;
    const float* cv = cv_all + (size_t)t*CAND_MAX;
    const int*   ci = ci_all + (size_t)t*CAND_MAX;
    int* topidx = topidx_all + t*128;
    float* tanhv = tanhv_all + t*128;
    int tid = threadIdx.x;
    int M = cnt_all[t*64]; if (M > CAND_MAX) M = CAND_MAX;
    for (int i = tid; i < M; i += 256)
        keys[i] = ((unsigned long long)f2key(cv[i]) << 32) | (unsigned)(~ci[i]);
    __syncthreads();
    for (int i = tid; i < M; i += 256){
        unsigned long long ki = keys[i];
        int r = 0;
        for (int j = 0; j < M; j++) r += (keys[j] > ki) ? 1 : 0;
        if (r < 76){
            topidx[r] = (int)(~(unsigned)(ki & 0xffffffffu));
            tanhv[r]  = tanhf(key2f((unsigned)(ki >> 32)));
        }
    }
}

// ---- GRU weight evolution, one block per matrix row, in-place; also emits Wt ----
template<int F>
__global__ void gru_k(const float* __restrict__ cur, const int* __restrict__ topidx,
                      const float* __restrict__ tanhv, float* __restrict__ W,
                      float* __restrict__ Wt,
                      const float* __restrict__ wih, const float* __restrict__ whh,
                      const float* __restrict__ bih, const float* __restrict__ bhh){
    __shared__ float xr[HID], hr[HID], gx[H3], gh[H3];
    int r = blockIdx.x, tid = threadIdx.x;
    if (tid < HID){
        xr[tid] = cur[(size_t)topidx[tid]*F + r] * tanhv[tid];
        hr[tid] = W[r*HID + tid];
    }
    __syncthreads();
    if (tid < H3){
        const float* wi = wih + tid*HID;
        const float* wh = whh + tid*HID;
        float sa = 0.f, sb = 0.f;
        for (int k = 0; k < HID; k++){ sa += xr[k]*wi[k]; sb += hr[k]*wh[k]; }
        gx[tid] = bih[tid] + sa;
        gh[tid] = bhh[tid] + sb;
    }
    __syncthreads();
    if (tid < HID){
        float rr = 1.f/(1.f + expf(-(gx[tid] + gh[tid])));
        float zz = 1.f/(1.f + expf(-(gx[HID+tid] + gh[HID+tid])));
        float nn = tanhf(gx[2*HID+tid] + rr*gh[2*HID+tid]);
        float nv = (1.f - zz)*nn + zz*hr[tid];
        W[r*HID + tid] = nv;
        int c = tid >> 2, i = tid & 3;
        Wt[(c*F + r)*4 + i] = nv;    // chunk layout for gemm_k
    }
}

// ---- h = (x @ W) * norm_out ----
template<int F, int PAD, int NB>
__global__ __launch_bounds__(256) void gemm_k(const float* __restrict__ x,
                                              const float* __restrict__ Wt,
                                              const float* __restrict__ nO,
                                              float* __restrict__ h){
    __shared__ __align__(16) float xs[NB*PAD];
    int tid = threadIdx.x;
    int n0 = blockIdx.x*NB;
    int nodes = NN - n0; if (nodes > NB) nodes = NB;
    for (int idx = tid; idx < nodes*F; idx += 256){
        int n = idx / F, k = idx - n*F;
        xs[n*PAD + k] = x[(size_t)(n0+n)*F + k];
    }
    __syncthreads();
    int w = __builtin_amdgcn_readfirstlane(tid >> 6);
    int lane = tid & 63;
    int c0 = w*5;
    const float4* Wt4 = (const float4*)Wt;
    float4 accA[5], accB[5];
    #pragma unroll
    for (int c = 0; c < 5; c++){
        accA[c] = make_float4(0.f,0.f,0.f,0.f);
        accB[c] = make_float4(0.f,0.f,0.f,0.f);
    }
    const float* xA = xs + lane*PAD;
    const float* xB = xs + ((NB==128) ? (lane+64)*PAD : lane*PAD);
    for (int k = 0; k < F; k++){
        float xa = xA[k];
        float xb = 0.f;
        if constexpr (NB == 128) xb = xB[k];
        #pragma unroll
        for (int c = 0; c < 5; c++){
            float4 wv = Wt4[(c0 + c)*F + k];
            accA[c].x += xa*wv.x; accA[c].y += xa*wv.y;
            accA[c].z += xa*wv.z; accA[c].w += xa*wv.w;
            if constexpr (NB == 128){
                accB[c].x += xb*wv.x; accB[c].y += xb*wv.y;
                accB[c].z += xb*wv.z; accB[c].w += xb*wv.w;
            }
        }
    }
    int nc = (w == 3) ? 4 : 5;
    int nA = n0 + lane;
    if (nA < NN){
        float nm = nO[nA];
        float4* h4 = (float4*)h + (size_t)nA*HPAD + c0;
        for (int c = 0; c < nc; c++){
            float4 a = accA[c];
            h4[c] = make_float4(a.x*nm, a.y*nm, a.z*nm, a.w*nm);
        }
    }
    if constexpr (NB == 128){
        int nB = n0 + 64 + lane;
        if (nB < NN){
            float nm = nO[nB];
            float4* h4 = (float4*)h + (size_t)nB*HPAD + c0;
            for (int c = 0; c < nc; c++){
                float4 a = accB[c];
                h4[c] = make_float4(a.x*nm, a.y*nm, a.z*nm, a.w*nm);
            }
        }
    }
}

// ---- CSR aggregation + dst-norm + leaky, thread per (node, float4 chunk) ----
// col band-sorted (p6) + bijective XCD swizzle + 8-deep gather unroll.
__global__ __launch_bounds__(256) void agg_k(const int* __restrict__ rs, const int* __restrict__ degI,
                      const int* __restrict__ col, const float* __restrict__ h,
                      const float* __restrict__ nI, float* __restrict__ ft){
    int b0 = blockIdx.x;
    int xcd = b0 & 7, i0 = b0 >> 3;
    const int q = AGG_NWG >> 3;          // 927
    const int r8 = AGG_NWG & 7;          // 6
    int bs = (xcd < r8) ? (xcd*(q+1) + i0) : (r8*(q+1) + (xcd - r8)*q + i0);
    int idx = bs*256 + threadIdx.x;
    if (idx >= NN*19) return;
    int n = idx/19, c = idx - n*19;
    int st = rs[n], cnt = degI[n];
    const float4* h4 = (const float4*)h;
    float ax=0.f, ay=0.f, az=0.f, aw=0.f;
    int e = 0;
    for (; e + 8 <= cnt; e += 8){
        int s0 = col[st + e];
        int s1 = col[st + e + 1];
        int s2 = col[st + e + 2];
        int s3 = col[st + e + 3];
        int s4 = col[st + e + 4];
        int s5 = col[st + e + 5];
        int s6 = col[st + e + 6];
        int s7 = col[st + e + 7];
        float4 v0 = h4[(size_t)s0*HPAD + c];
        float4 v1 = h4[(size_t)s1*HPAD + c];
        float4 v2 = h4[(size_t)s2*HPAD + c];
        float4 v3 = h4[(size_t)s3*HPAD + c];
        float4 v4 = h4[(size_t)s4*HPAD + c];
        float4 v5 = h4[(size_t)s5*HPAD + c];
        float4 v6 = h4[(size_t)s6*HPAD + c];
        float4 v7 = h4[(size_t)s7*HPAD + c];
        ax += ((v0.x + v1.x) + (v2.x + v3.x)) + ((v4.x + v5.x) + (v6.x + v7.x));
        ay += ((v0.y + v1.y) + (v2.y + v3.y)) + ((v4.y + v5.y) + (v6.y + v7.y));
        az += ((v0.z + v1.z) + (v2.z + v3.z)) + ((v4.z + v5.z) + (v6.z + v7.z));
        aw += ((v0.w + v1.w) + (v2.w + v3.w)) + ((v4.w + v5.w) + (v6.w + v7.w));
    }
    for (; e + 2 <= cnt; e += 2){
        int s0 = col[st + e];
        int s1 = col[st + e + 1];
        float4 v0 = h4[(size_t)s0*HPAD + c];
        float4 v1 = h4[(size_t)s1*HPAD + c];
        ax += v0.x + v1.x; ay += v0.y + v1.y;
        az += v0.z + v1.z; aw += v0.w + v1.w;
    }
    if (e < cnt){
        int s = col[st + e];
        float4 v = h4[(size_t)s*HPAD + c];
        ax += v.x; ay += v.y; az += v.z; aw += v.w;
    }
    float nm = nI[n];
    ax*=nm; ay*=nm; az*=nm; aw*=nm;
    ax = ax >= 0.f ? ax : ax*SLOPE;
    ay = ay >= 0.f ? ay : ay*SLOPE;
    az = az >= 0.f ? az : az*SLOPE;
    aw = aw >= 0.f ? aw : aw*SLOPE;
    ((float4*)ft)[(size_t)n*19 + c] = make_float4(ax,ay,az,aw);
}

// ---- classifier MLP (measured best: 192us): register-tiled GEMM, both operands
// lane-distributed from LDS; 8x8 tile/lane, 1:16 read:FMA; 2 j-halves staged.
__global__ __launch_bounds__(512) void mlp3_k(const float* __restrict__ ft,
                                              const float* __restrict__ w1t,
                                              const float* __restrict__ b1p,
                                              const float* __restrict__ w2p,
                                              const float* __restrict__ b2,
                                              float* __restrict__ out){
    __shared__ __align__(16) float xs[128*HID];      // 38912 B (reused for reduction)
    __shared__ __align__(16) float ws[256*HID];      // 77824 B
    __shared__ float b1s[512];
    __shared__ float w2s[1024];
    int tid = threadIdx.x;
    int n0 = blockIdx.x*128;
    {
        int lim = ((NN - n0 < 128) ? (NN - n0) : 128)*19;
        const float4* g4 = (const float4*)(ft + (size_t)n0*HID);
        float4* s4 = (float4*)xs;
        for (int i = tid; i < 128*19; i += 512)
            s4[i] = (i < lim) ? g4[i] : make_float4(0.f,0.f,0.f,0.f);
    }
    b1s[tid] = b1p[tid];
    for (int i = tid; i < 1024; i += 512) w2s[i] = w2p[i];
    int wid = tid >> 6, lane = tid & 63;
    int wr = wid >> 2, wc = wid & 3;
    int a = lane >> 3, b = lane & 7;
    float p0[8], p1[8];
    #pragma unroll
    for (int i = 0; i < 8; i++){ p0[i] = 0.f; p1[i] = 0.f; }
    const float4* xbase = (const float4*)(xs + (wr*64 + a)*HID);
    for (int jb = 0; jb < 2; jb++){
        __syncthreads();   // xs staged (jb=0) / ws readers done (jb=1)
        {
            const float4* g4 = (const float4*)(w1t + (size_t)jb*256*HID);
            float4* s4 = (float4*)ws;
            for (int i = tid; i < 256*19; i += 512) s4[i] = g4[i];
        }
        __syncthreads();
        float acc[8][8];
        #pragma unroll
        for (int i = 0; i < 8; i++)
            #pragma unroll
            for (int m = 0; m < 8; m++) acc[i][m] = 0.f;
        const float4* wbase = (const float4*)(ws + (wc*64 + b)*HID);
        for (int k4 = 0; k4 < 19; k4++){
            float4 xv[8], wv[8];
            #pragma unroll
            for (int i = 0; i < 8; i++) xv[i] = xbase[i*(8*19) + k4];
            #pragma unroll
            for (int m = 0; m < 8; m++) wv[m] = wbase[m*(8*19) + k4];
            #pragma unroll
            for (int i = 0; i < 8; i++)
                #pragma unroll
                for (int m = 0; m < 8; m++){
                    acc[i][m] += xv[i].x*wv[m].x + xv[i].y*wv[m].y
                               + xv[i].z*wv[m].z + xv[i].w*wv[m].w;
                }
        }
        #pragma unroll
        for (int m = 0; m < 8; m++){
            int j = jb*256 + wc*64 + b + 8*m;
            float bias = b1s[j];
            float u0 = w2s[2*j], u1 = w2s[2*j+1];
            #pragma unroll
            for (int i = 0; i < 8; i++){
                float s = acc[i][m] + bias;
                s = fmaxf(s, 0.f);
                p0[i] += s*u0;
                p1[i] += s*u1;
            }
        }
    }
    // reduce over b (lanes a*8..a*8+7)
    #pragma unroll
    for (int off = 1; off < 8; off <<= 1){
        #pragma unroll
        for (int i = 0; i < 8; i++){
            p0[i] += __shfl_xor(p0[i], off, 64);
            p1[i] += __shfl_xor(p1[i], off, 64);
        }
    }
    __syncthreads();   // all k-loop reads of xs complete -> safe to overlay
    float* red = xs;   // [wc][128 node][2] = 4KB
    if (b == 0){
        #pragma unroll
        for (int i = 0; i < 8; i++){
            int nl = wr*64 + a + 8*i;
            red[(wc*128 + nl)*2 + 0] = p0[i];
            red[(wc*128 + nl)*2 + 1] = p1[i];
        }
    }
    __syncthreads();
    if (tid < 256){
        int nl = tid >> 1, comp = tid & 1;
        float v = red[(0*128 + nl)*2 + comp] + red[(1*128 + nl)*2 + comp]
                + red[(2*128 + nl)*2 + comp] + red[(3*128 + nl)*2 + comp] + b2[comp];
        int n = n0 + nl;
        if (n < NN) out[(size_t)n*2 + comp] = v;
    }
}

extern "C" void kernel_launch(void* const* d_in, const int* in_sizes, int n_in,
                              void* d_out, int out_size, void* d_ws, size_t ws_size,
                              hipStream_t stream)
{
    (void)in_sizes; (void)n_in; (void)out_size; (void)ws_size;
    const float* feats   = (const float*)d_in[0];
    const int*   src     = (const int*)d_in[1];
    const int*   dst     = (const int*)d_in[2];
    const float* scorer0 = (const float*)d_in[3];
    const float* scorer1 = (const float*)d_in[4];
    const float* gcnw[2] = {(const float*)d_in[5],  (const float*)d_in[6]};
    const float* wih[2]  = {(const float*)d_in[7],  (const float*)d_in[11]};
    const float* whh[2]  = {(const float*)d_in[8],  (const float*)d_in[12]};
    const float* bih[2]  = {(const float*)d_in[9],  (const float*)d_in[13]};
    const float* bhh[2]  = {(const float*)d_in[10], (const float*)d_in[14]};
    const float* w1 = (const float*)d_in[15];
    const float* b1 = (const float*)d_in[16];
    const float* w2 = (const float*)d_in[17];
    const float* b2 = (const float*)d_in[18];
    float* out = (float*)d_out;

    char* p = (char*)d_ws;
    auto alloc = [&](size_t bytes) -> void* {
        void* r = (void*)p;
        p += (bytes + 255) & ~(size_t)255;
        return r;
    };
    // ft as ONE contiguous buffer so batched score can stride by t
    float* ft_all = (float*)alloc((size_t)3*NN*HID*4);
    float* hbuf    = (float*)alloc((size_t)NN*HPAD*16);
    int*   col_all = (int*)alloc((size_t)3*EE*4);
    float* nO_all  = (float*)alloc((size_t)3*NN*4);
    float* nI_all  = (float*)alloc((size_t)3*NN*4);
    int*   rs_all  = (int*)alloc((size_t)3*NN*4);
    int*   dI_all  = (int*)alloc((size_t)3*NN*4);
    // partition workspace
    int* srcpart = (int*)alloc((size_t)3*EE*4);
    unsigned* pairpart = (unsigned*)alloc((size_t)3*EE*4);
    int* bhS = (int*)alloc((size_t)3*NBKT*NCHK*4);
    int* bhD = (int*)alloc((size_t)3*NBKT*NCHK*4);
    int* ctS = (int*)alloc((size_t)3*NBKT*4);
    int* ctD = (int*)alloc((size_t)3*NBKT*4);
    int* bbS = (int*)alloc((size_t)3*(NBKT+1)*4);
    int* bbD = (int*)alloc((size_t)3*(NBKT+1)*4);

    float*    scores3 = (float*)alloc((size_t)3*NN*4);
    float*    cv3     = (float*)alloc((size_t)3*CAND_MAX*4);
    int*      ci3     = (int*)alloc((size_t)3*CAND_MAX*4);
    int*      topidx3 = (int*)alloc(3*128*4);
    float*    tanhv3  = (float*)alloc(3*128*4);
    float*    Wbuf    = (float*)alloc((size_t)F0*HID*4 + 256);
    float*    Wt      = (float*)alloc((size_t)19*F0*16 + 4096);
    float*    invn    = (float*)alloc(256);
    float*    w1t     = (float*)alloc((size_t)512*HID*4);
    float*    b1p     = (float*)alloc(512*4);
    float*    w2p     = (float*)alloc(1024*4);

    // ---- contiguous zero arena (one memset) ----
    char* zbase = p;
    unsigned* hist6 = (unsigned*)alloc((size_t)6*NBIN*4);
    int*      ccnt6 = (int*)alloc(6*256);
    size_t zsize = (size_t)(p - zbase);

    const int gN  = (NN + 255)/256;
    const int gB  = (NN + 63)/64;
    const int gB2 = (NN + 127)/128;
    const int gM  = (NN + 127)/128;
    const int gP  = (512*HID + 255)/256;

    hipMemsetAsync(zbase, 0, zsize, stream);
    scorer_norms_k<<<1,256,0,stream>>>(scorer0, scorer1, invn);
    pad_k<<<gP,256,0,stream>>>(w1, b1, w2, w1t, b1p, w2p);

    // ---- bucket-partition CSR build (no global atomics) ----
    p1_hist_k<<<dim3(NCHK,3),256,0,stream>>>(src, dst, bhS, bhD);
    p2_scan_k<<<dim3(NBKT,3),512,0,stream>>>(bhS, bhD, ctS, ctD);
    p3_base_k<<<1,256,0,stream>>>(ctS, ctD, bbS, bbD);
    p4_scatter_k<<<dim3(NCHK,3),256,0,stream>>>(src, dst, bhS, bhD, bbS, bbD, srcpart, pairpart);
    p5_degO_k<<<dim3(NBKT,3),256,0,stream>>>(srcpart, bbS, nO_all);
    p6_csr_k<<<dim3(NBKT,3),512,0,stream>>>(pairpart, bbD, dI_all, rs_all, nI_all, col_all);

    for (int i = 0; i < 2; i++){
        hipMemcpyAsync(Wbuf, gcnw[i], (size_t)((i==0)?F0:HID)*HID*4, hipMemcpyDeviceToDevice, stream);
        // batched selection phase: all 3 t's independent at layer start
        unsigned* hist3 = hist6 + (size_t)i*3*NBIN;
        int*      cnt3  = ccnt6 + i*3*64;
        if (i == 0) score_k<F0,167><<<dim3(gB,3),256,0,stream>>>(feats, scorer0, invn+0, scores3, hist3);
        else        score_k<HID,77><<<dim3(gB,3),256,0,stream>>>(ft_all, scorer1, invn+1, scores3, hist3);
        compact_k<<<dim3(gN,3),256,0,stream>>>(scores3, hist3, cv3, ci3, cnt3);
        topk_k<<<3,256,0,stream>>>(cv3, ci3, cnt3, topidx3, tanhv3);
        for (int t = 0; t < 3; t++){
            const float* cur = (i == 0) ? (feats + (size_t)t*NN*F0) : (ft_all + (size_t)t*NN*HID);
            if (i == 0){
                gru_k<F0><<<F0,256,0,stream>>>(cur, topidx3 + t*128, tanhv3 + t*128,
                                               Wbuf, Wt, wih[i], whh[i], bih[i], bhh[i]);
                gemm_k<F0,167,64><<<gB,256,0,stream>>>(cur, Wt, nO_all + (size_t)t*NN, hbuf);
            } else {
                gru_k<HID><<<HID,256,0,stream>>>(cur, topidx3 + t*128, tanhv3 + t*128,
                                                 Wbuf, Wt, wih[i], whh[i], bih[i], bhh[i]);
                gemm_k<HID,77,128><<<gB2,256,0,stream>>>(cur, Wt, nO_all + (size_t)t*NN, hbuf);
            }
            agg_k<<<AGG_NWG,256,0,stream>>>(rs_all + (size_t)t*NN, dI_all + (size_t)t*NN,
                                            col_all + (size_t)t*EE, hbuf, nI_all + (size_t)t*NN,
                                            ft_all + (size_t)t*NN*HID);
        }
    }

    mlp3_k<<<gM,512,0,stream>>>(ft_all + (size_t)2*NN*HID, w1t, b1p, w2p, b2, out);
}